// Round 4
// baseline (1057.826 us; speedup 1.0000x reference)
//
#include <hip/hip_runtime.h>
#include <hip/hip_bf16.h>

typedef __attribute__((ext_vector_type(8))) short short8;
typedef __attribute__((ext_vector_type(4))) float f32x4;

__device__ __forceinline__ unsigned short f2bf(float f){
  __hip_bfloat16 h = __float2bfloat16(f);
  return *reinterpret_cast<unsigned short*>(&h);
}

__device__ __forceinline__ float gelu_t(float x){
  // jax.nn.gelu default (approximate=True)
  float u = 0.7978845608028654f * (x + 0.044715f * x * x * x);
  float e = __expf(2.0f * u);
  float t = 1.0f - 2.0f / (e + 1.0f);
  return 0.5f * x * (1.0f + t);
}

// ---------------- histogram ----------------
__global__ void k_hist(const int* __restrict__ sp, int* __restrict__ cnt, int N){
  int i = blockIdx.x * blockDim.x + threadIdx.x;
  if (i < N) atomicAdd(&cnt[sp[i]], 1);
}

// ---------------- exclusive scan (single block) ----------------
__global__ void k_scan(const int* __restrict__ cnt, int* __restrict__ starts, int S){
  __shared__ int part[256];
  int tid = threadIdx.x;
  int chunk = (S + 255) / 256;
  int lo = tid * chunk;
  int hi = min(lo + chunk, S);
  int sum = 0;
  for (int i = lo; i < hi; i++) sum += cnt[i];
  part[tid] = sum;
  __syncthreads();
  if (tid == 0){
    int run = 0;
    for (int i = 0; i < 256; i++){ int v = part[i]; part[i] = run; run += v; }
  }
  __syncthreads();
  int run = part[tid];
  for (int i = lo; i < hi; i++){ starts[i] = run; run += cnt[i]; }
}

// ---------------- scatter (arbitrary order within segment) ----------------
__global__ void k_scatter(const int* __restrict__ sp, const int* __restrict__ starts,
                          int* __restrict__ fill, int* __restrict__ perm, int N){
  int i = blockIdx.x * blockDim.x + threadIdx.x;
  if (i < N){
    int s = sp[i];
    int pos = atomicAdd(&fill[s], 1);
    perm[starts[s] + pos] = i;
  }
}

// ---------------- stable rank fix: one wave per superpoint ----------------
#define MAXC 512
__global__ void k_rank(const int* __restrict__ perm, const int* __restrict__ starts,
                       const int* __restrict__ cnt, int* __restrict__ perm2, int S){
  __shared__ int buf[4][MAXC];
  int wv = threadIdx.x >> 6;
  int lane = threadIdx.x & 63;
  int s = blockIdx.x * 4 + wv;
  int st = 0, c = 0;
  if (s < S){ st = starts[s]; c = cnt[s]; }
  if (c <= MAXC){
    for (int j = lane; j < c; j += 64) buf[wv][j] = perm[st + j];
  }
  __syncthreads();
  if (c <= MAXC){
    for (int j = lane; j < c; j += 64){
      int v = buf[wv][j];
      int r = 0;
      for (int m = 0; m < c; m++) r += (buf[wv][m] < v) ? 1 : 0;
      perm2[st + r] = v;   // stable order = ascending original index
    }
  } else {
    for (int j = lane; j < c; j += 64) perm2[st + j] = perm[st + j];
  }
}

// ---------------- fused pool + sample: one block (256 thr) per superpoint ----------------
// Streams segment rows once (mean), then re-emits the K sampled rows (cache-hot)
// and the mean token, all as bf16 directly into seq. Kills k_seq + xsp round-trip.
#define KMAX 16
__global__ __launch_bounds__(256)
void k_pool(const float* __restrict__ raw, const int* __restrict__ perm2,
            const int* __restrict__ starts, const int* __restrict__ cnt,
            const int* __restrict__ rnd, unsigned short* __restrict__ seq,
            int S, int K, int N){
  __shared__ int lidx[MAXC];
  __shared__ float red[4][64][4];
  __shared__ int tgt[KMAX];
  int s = blockIdx.x;
  int tid = threadIdx.x;
  int lane = tid & 63;
  int wv = tid >> 6;
  int st = starts[s], c = cnt[s];
  int cc = min(c, MAXC);

  for (int m = tid; m < cc; m += 256) lidx[m] = perm2[st + m];
  if (tid < K){
    int ml = max(c, 1);
    tgt[tid] = rnd[s * K + tid] % ml;
  }
  __syncthreads();

  // phase 1: mean over segment rows, 4-deep unrolled pipeline per wave
  float4 a0 = {0,0,0,0}, a1 = {0,0,0,0}, a2 = {0,0,0,0}, a3 = {0,0,0,0};
  const float4* rawv = reinterpret_cast<const float4*>(raw);
  int m = wv;
  for (; m + 12 < c; m += 16){
    int i0 = (m      < MAXC) ? lidx[m]      : perm2[st + m];
    int i1 = (m + 4  < MAXC) ? lidx[m + 4]  : perm2[st + m + 4];
    int i2 = (m + 8  < MAXC) ? lidx[m + 8]  : perm2[st + m + 8];
    int i3 = (m + 12 < MAXC) ? lidx[m + 12] : perm2[st + m + 12];
    float4 v0 = rawv[(size_t)i0 * 64 + lane];
    float4 v1 = rawv[(size_t)i1 * 64 + lane];
    float4 v2 = rawv[(size_t)i2 * 64 + lane];
    float4 v3 = rawv[(size_t)i3 * 64 + lane];
    a0.x += v0.x; a0.y += v0.y; a0.z += v0.z; a0.w += v0.w;
    a1.x += v1.x; a1.y += v1.y; a1.z += v1.z; a1.w += v1.w;
    a2.x += v2.x; a2.y += v2.y; a2.z += v2.z; a2.w += v2.w;
    a3.x += v3.x; a3.y += v3.y; a3.z += v3.z; a3.w += v3.w;
  }
  for (; m < c; m += 4){
    int i0 = (m < MAXC) ? lidx[m] : perm2[st + m];
    float4 v0 = rawv[(size_t)i0 * 64 + lane];
    a0.x += v0.x; a0.y += v0.y; a0.z += v0.z; a0.w += v0.w;
  }
  float4 acc;
  acc.x = (a0.x + a1.x) + (a2.x + a3.x);
  acc.y = (a0.y + a1.y) + (a2.y + a3.y);
  acc.z = (a0.z + a1.z) + (a2.z + a3.z);
  acc.w = (a0.w + a1.w) + (a2.w + a3.w);
  red[wv][lane][0] = acc.x; red[wv][lane][1] = acc.y;
  red[wv][lane][2] = acc.z; red[wv][lane][3] = acc.w;
  __syncthreads();

  size_t tokbase = (size_t)s * (K + 1);
  if (wv == 0){
    float inv = 1.0f / (float)max(c, 1);
    float4 o;
    o.x = (red[0][lane][0] + red[1][lane][0] + red[2][lane][0] + red[3][lane][0]) * inv;
    o.y = (red[0][lane][1] + red[1][lane][1] + red[2][lane][1] + red[3][lane][1]) * inv;
    o.z = (red[0][lane][2] + red[1][lane][2] + red[2][lane][2] + red[3][lane][2]) * inv;
    o.w = (red[0][lane][3] + red[1][lane][3] + red[2][lane][3] + red[3][lane][3]) * inv;
    ushort4 ob;
    ob.x = f2bf(o.x); ob.y = f2bf(o.y); ob.z = f2bf(o.z); ob.w = f2bf(o.w);
    reinterpret_cast<ushort4*>(seq)[(tokbase + K) * 64 + lane] = ob;
  }

  // phase 2: sampled rows (cache-hot — just streamed by this block)
  for (int j = wv; j < K; j += 4){
    int g = tgt[j];
    int idx;
    if (g < cc) idx = lidx[g];
    else        idx = perm2[min(st + g, N - 1)];
    float4 v = rawv[(size_t)idx * 64 + lane];
    ushort4 o;
    o.x = f2bf(v.x); o.y = f2bf(v.y); o.z = f2bf(v.z); o.w = f2bf(v.w);
    reinterpret_cast<ushort4*>(seq)[(tokbase + j) * 64 + lane] = o;
  }
}

// ---------------- transpose-cast fp32 [A][B] -> bf16 [B][A] ----------------
__global__ void k_castT(const float* __restrict__ in, unsigned short* __restrict__ out,
                        int A, int B){
  int i = blockIdx.x * blockDim.x + threadIdx.x;
  if (i >= A * B) return;
  int b = i / A, a = i - b * A;
  out[(size_t)b * A + a] = f2bf(in[(size_t)a * B + b]);
}

// ---------------- fused MLP v3 ----------------
// 64 tokens/block, 8 waves (512 thr). LDS (bf16, XOR-swizzled granule^row&7):
//   seq [64][256], w1 [64][256], h [64][64]  => 73728 B => 2 blocks/CU.
// A-fragments (seq) hoisted into registers once — identical across all 16 chunks.
// w2 B-fragments read directly from global (L2-resident), prefetched per chunk.
__global__ __launch_bounds__(512, 4)
void k_mlp(const unsigned short* __restrict__ seq, const unsigned short* __restrict__ w1t,
           const unsigned short* __restrict__ w2t, const float* __restrict__ bias1,
           const float* __restrict__ bias2, float* __restrict__ out, int Ttot){
  extern __shared__ char ldsraw[];
  unsigned short* seq_lds = (unsigned short*)ldsraw;        // [64][256]
  unsigned short* w1_lds  = seq_lds + 64 * 256;             // [64][256]
  unsigned short* h_lds   = w1_lds + 64 * 256;              // [64][64]

  const int tid  = threadIdx.x;
  const int lane = tid & 63;
  const int wv   = tid >> 6;       // 0..7
  const int tg   = wv & 3;         // token group for GEMM1
  const int hh   = wv >> 2;        // hidden half for GEMM1
  const int l15  = lane & 15;
  const int lhi  = lane >> 4;      // 0..3
  const int t0   = blockIdx.x * 64;

  // stage seq tile (swizzled)
  #pragma unroll
  for (int rpt = 0; rpt < 4; rpt++){
    int idx = rpt * 512 + tid;           // 0..2047 granules
    int row = idx >> 5, gr = idx & 31;
    int t = t0 + row;
    int4 v = make_int4(0, 0, 0, 0);
    if (t < Ttot) v = *reinterpret_cast<const int4*>(seq + (size_t)t * 256 + gr * 8);
    *reinterpret_cast<int4*>(seq_lds + row * 256 + ((gr ^ (row & 7)) << 3)) = v;
  }
  __syncthreads();

  // hoist A-fragments: same for every hidden chunk (32 VGPRs)
  short8 afrag[8];
  const int arow = tg * 16 + l15;
  #pragma unroll
  for (int ks = 0; ks < 8; ks++){
    int agr = (ks * 4 + lhi) ^ (arow & 7);
    afrag[ks] = *reinterpret_cast<const short8*>(seq_lds + arow * 256 + agr * 8);
  }

  f32x4 acc2[4][2];
  #pragma unroll
  for (int rf = 0; rf < 4; rf++)
    #pragma unroll
    for (int cf = 0; cf < 2; cf++) acc2[rf][cf] = (f32x4){0.f, 0.f, 0.f, 0.f};

  for (int c = 0; c < 16; c++){
    __syncthreads();   // prev iter's w1/h consumers done

    // stage w1 chunk c (swizzled)
    #pragma unroll
    for (int rpt = 0; rpt < 4; rpt++){
      int idx = rpt * 512 + tid;
      int row = idx >> 5, gr = idx & 31;
      int4 v = *reinterpret_cast<const int4*>(w1t + (size_t)(c * 64 + row) * 256 + gr * 8);
      *reinterpret_cast<int4*>(w1_lds + row * 256 + ((gr ^ (row & 7)) << 3)) = v;
    }

    // prefetch w2 fragments + bias1 (regs; latency hides under staging/barrier)
    short8 w2f[2][2];
    #pragma unroll
    for (int cf = 0; cf < 2; cf++)
      #pragma unroll
      for (int ks = 0; ks < 2; ks++)
        w2f[cf][ks] = *reinterpret_cast<const short8*>(
            w2t + (size_t)(wv * 32 + cf * 16 + l15) * 1024 + c * 64 + ks * 32 + lhi * 8);
    float bv1[2];
    bv1[0] = bias1[c * 64 + hh * 32 + l15];
    bv1[1] = bias1[c * 64 + hh * 32 + 16 + l15];

    __syncthreads();   // w1 tile ready

    // GEMM1: tokens [tg*16,+16) x hid cols [hh*32,+32), K=256 (A from regs)
    f32x4 acc1[2];
    acc1[0] = (f32x4){0.f, 0.f, 0.f, 0.f};
    acc1[1] = (f32x4){0.f, 0.f, 0.f, 0.f};
    #pragma unroll
    for (int ks = 0; ks < 8; ks++){
      #pragma unroll
      for (int fc = 0; fc < 2; fc++){
        int brow = hh * 32 + fc * 16 + l15;
        int bgr = (ks * 4 + lhi) ^ (brow & 7);
        short8 b = *reinterpret_cast<const short8*>(w1_lds + brow * 256 + bgr * 8);
        acc1[fc] = __builtin_amdgcn_mfma_f32_16x16x32_bf16(afrag[ks], b, acc1[fc], 0, 0, 0);
      }
    }
    // bias + GELU -> h (swizzled b16 writes)
    #pragma unroll
    for (int fc = 0; fc < 2; fc++){
      int col = hh * 32 + fc * 16 + l15;
      #pragma unroll
      for (int q = 0; q < 4; q++){
        int row = tg * 16 + lhi * 4 + q;
        float v = acc1[fc][q] + bv1[fc];
        int phys = (col >> 3) ^ (row & 7);
        h_lds[row * 64 + phys * 8 + (col & 7)] = f2bf(gelu_t(v));
      }
    }
    __syncthreads();   // h ready

    // GEMM2: out rows [0,64) x cols [wv*32,+32), K=64 (chunk), accumulate
    #pragma unroll
    for (int ks = 0; ks < 2; ks++){
      short8 af[4];
      #pragma unroll
      for (int rf = 0; rf < 4; rf++){
        int hrow = rf * 16 + l15;
        int hgr = (ks * 4 + lhi) ^ (hrow & 7);
        af[rf] = *reinterpret_cast<const short8*>(h_lds + hrow * 64 + hgr * 8);
      }
      #pragma unroll
      for (int cf = 0; cf < 2; cf++)
        #pragma unroll
        for (int rf = 0; rf < 4; rf++)
          acc2[rf][cf] = __builtin_amdgcn_mfma_f32_16x16x32_bf16(af[rf], w2f[cf][ks],
                                                                 acc2[rf][cf], 0, 0, 0);
    }
  }

  // epilogue: out[t][d] = acc2 + b2 (fp32)
  #pragma unroll
  for (int cf = 0; cf < 2; cf++){
    int dcol = wv * 32 + cf * 16 + l15;
    float bv = bias2[dcol];
    #pragma unroll
    for (int rf = 0; rf < 4; rf++){
      #pragma unroll
      for (int q = 0; q < 4; q++){
        int t = t0 + rf * 16 + lhi * 4 + q;
        if (t < Ttot) out[(size_t)t * 256 + dcol] = acc2[rf][cf][q] + bv;
      }
    }
  }
}

extern "C" void kernel_launch(void* const* d_in, const int* in_sizes, int n_in,
                              void* d_out, int out_size, void* d_ws, size_t ws_size,
                              hipStream_t stream){
  const float* raw = (const float*)d_in[0];
  const float* w1  = (const float*)d_in[1];
  const float* b1  = (const float*)d_in[2];
  const float* w2  = (const float*)d_in[3];
  const float* b2  = (const float*)d_in[4];
  const int* sp    = (const int*)d_in[5];
  const int* rnd   = (const int*)d_in[6];

  const int N    = in_sizes[5];          // 500000
  const int D    = in_sizes[0] / N;      // 256
  const int HID  = in_sizes[2];          // 1024
  const int SK   = in_sizes[6];          // S*K
  const int Ttot = out_size / D;         // S*(K+1)
  const int S    = Ttot - SK;            // 10000
  const int K    = SK / S;               // 10

  char* ws = (char*)d_ws;
  size_t off = 0;
  auto alloc = [&](size_t bytes) -> char* {
    char* p = ws + off;
    off += (bytes + 255) & ~(size_t)255;
    return p;
  };
  int* cnt    = (int*)alloc((size_t)S * 4);
  int* fill   = (int*)alloc((size_t)S * 4);
  int* starts = (int*)alloc((size_t)S * 4);
  int* perm   = (int*)alloc((size_t)N * 4);
  int* perm2  = (int*)alloc((size_t)N * 4);
  unsigned short* w1t = (unsigned short*)alloc((size_t)D * HID * 2);
  unsigned short* w2t = (unsigned short*)alloc((size_t)HID * D * 2);
  unsigned short* seq = (unsigned short*)alloc((size_t)(S * (K + 1)) * D * 2);

  hipMemsetAsync(cnt, 0, (size_t)S * 4, stream);
  hipMemsetAsync(fill, 0, (size_t)S * 4, stream);

  int nb = (N + 255) / 256;
  k_hist<<<nb, 256, 0, stream>>>(sp, cnt, N);
  k_scan<<<1, 256, 0, stream>>>(cnt, starts, S);
  k_scatter<<<nb, 256, 0, stream>>>(sp, starts, fill, perm, N);
  k_rank<<<(S + 3) / 4, 256, 0, stream>>>(perm, starts, cnt, perm2, S);
  k_castT<<<(D * HID + 255) / 256, 256, 0, stream>>>(w1, w1t, D, HID);
  k_castT<<<(HID * D + 255) / 256, 256, 0, stream>>>(w2, w2t, HID, D);
  k_pool<<<S, 256, 0, stream>>>(raw, perm2, starts, cnt, rnd, seq, S, K, N);

  int mlpBlocks = (Ttot + 63) / 64;
  size_t ldsBytes = (size_t)(64 * 256 + 64 * 256 + 64 * 64) * sizeof(unsigned short); // 73728
  hipFuncSetAttribute((const void*)k_mlp, hipFuncAttributeMaxDynamicSharedMemorySize,
                      (int)ldsBytes);
  k_mlp<<<mlpBlocks, 512, ldsBytes, stream>>>(seq, w1t, w2t, b1, b2, (float*)d_out, Ttot);
}